// Round 3
// baseline (324.366 us; speedup 1.0000x reference)
//
#include <hip/hip_runtime.h>

typedef __attribute__((ext_vector_type(8))) short short8;     // 8 x bf16 (4 VGPRs) MFMA frag
typedef __attribute__((ext_vector_type(4))) float floatx4;    // MFMA accumulator
typedef unsigned short u16;
typedef unsigned int   u32;

__device__ __forceinline__ u32 f2bf(float f) {               // fp32 -> bf16, round-to-nearest-even
  u32 u = __float_as_uint(f);
  return (u + 0x7fffu + ((u >> 16) & 1u)) >> 16;
}

__device__ __forceinline__ short8 cvt8(const float* f) {     // 8 fp32 -> bf16x8 fragment
  short8 r;
#pragma unroll
  for (int j = 0; j < 8; j++) r[j] = (short)f2bf(f[j]);
  return r;
}

// ---------------------------------------------------------------------------
// Householder precompute: one wave builds Q (64x64, fp32) sequentially,
// writes Q and Q^T as bf16 into workspace. Thread j owns column j in VGPRs.
// ---------------------------------------------------------------------------
__global__ void __launch_bounds__(64) hh_kernel(const float* __restrict__ vs,
                                                u16* __restrict__ Qb,
                                                u16* __restrict__ Qtb) {
  const int j = threadIdx.x;
  float col[64];
#pragma unroll
  for (int i = 0; i < 64; i++) col[i] = (i == j) ? 1.f : 0.f;

  __shared__ float v[64];
#pragma unroll 1
  for (int r = 0; r < 32; r++) {
    __syncthreads();
    v[j] = vs[r * 64 + j];
    __syncthreads();
    float vv0 = 0, vv1 = 0, vv2 = 0, vv3 = 0, w0 = 0, w1 = 0, w2 = 0, w3 = 0;
#pragma unroll
    for (int i = 0; i < 64; i += 4) {
      float a0 = v[i], a1 = v[i + 1], a2 = v[i + 2], a3 = v[i + 3];
      vv0 += a0 * a0; vv1 += a1 * a1; vv2 += a2 * a2; vv3 += a3 * a3;
      w0 += a0 * col[i]; w1 += a1 * col[i + 1]; w2 += a2 * col[i + 2]; w3 += a3 * col[i + 3];
    }
    float coef = 2.f / (((vv0 + vv1) + (vv2 + vv3)) + 1e-8f);
    float cw = coef * ((w0 + w1) + (w2 + w3));
#pragma unroll
    for (int i = 0; i < 64; i++) col[i] -= v[i] * cw;
  }
#pragma unroll
  for (int i = 0; i < 64; i++) {
    Qb [i * 64 + j] = (u16)f2bf(col[i]);   // Q[i][j]
    Qtb[j * 64 + i] = (u16)f2bf(col[i]);   // Q^T
  }
}

// ---------------------------------------------------------------------------
// Main kernel: ONE 16-token tile per wave, straight-line body, all global
// loads hoisted to the top (single stall point). 32768 tiles = 32768 waves.
//   GEMM1: qi^T = Q * x^T   (A = Q rows from global [L1-hot], B = token rows)
//   RoPE : lane-local fp32
//   GEMM2: out^T = Q^T * qr^T (B via bf16 LDS round-trip, stride-66 padding)
// ---------------------------------------------------------------------------
__global__ void __launch_bounds__(256, 5) rnrope_kernel(
    const float* __restrict__ qp, const float* __restrict__ kp,
    const float* __restrict__ cosp, const float* __restrict__ sinp,
    const u16* __restrict__ Qb, const u16* __restrict__ Qtb,
    float* __restrict__ outp) {
  const int lane = threadIdx.x & 63;
  const int t    = lane & 15;    // token within tile (B-operand n / D col)
  const int quad = lane >> 4;    // k-subblock selector
  const int widx = threadIdx.x >> 6;
  const int tile = blockIdx.x * 4 + widx;         // 0..32767

  // per-wave LDS: 16 rows x stride 66 u16 (33 words == 1 mod 32 -> conflict-free)
  __shared__ alignas(16) u16 sh_all[4][1056];
  u16* sh = sh_all[widx];

  const int tt   = tile & 16383;
  const bool isq = (tile < 16384);
  const float* __restrict__ inp = isq ? qp : kp;
  float* __restrict__ op = outp + (isq ? 0 : 16777216);
  const int token_base = tt * 16;
  const int s = token_base & 4095;                // tile never crosses (b,h) boundary
  const int b = token_base >> 16;                 // 65536 tokens per b
  const float* crow = cosp + ((b << 12) + s + t) * 64;
  const float* srow = sinp + ((b << 12) + s + t) * 64;
  const float* xrow = inp + (token_base + t) * 64;

  // ---- issue ALL independent global loads up front ----
  float xb[16];
  *(float4*)&xb[0]  = *(const float4*)(xrow + quad * 8);
  *(float4*)&xb[4]  = *(const float4*)(xrow + quad * 8 + 4);
  *(float4*)&xb[8]  = *(const float4*)(xrow + 32 + quad * 8);
  *(float4*)&xb[12] = *(const float4*)(xrow + 32 + quad * 8 + 4);

  float4 c[4], sn[4];
#pragma unroll
  for (int i0 = 0; i0 < 4; i0++) {
    c [i0] = *(const float4*)(crow + i0 * 16 + quad * 4);
    sn[i0] = *(const float4*)(srow + i0 * 16 + quad * 4);
  }

  // A-operand fragments (8 KB tables, L1-resident after first wave):
  short8 aQ[4][2];
#pragma unroll
  for (int i0 = 0; i0 < 4; i0++) {
#pragma unroll
    for (int ks = 0; ks < 2; ks++)
      aQ[i0][ks] = *(const short8*)(Qb + (i0 * 16 + t) * 64 + ks * 32 + quad * 8);
  }

  // ---- GEMM1 ----
  short8 bq0 = cvt8(&xb[0]);   // k = 0..31
  short8 bq1 = cvt8(&xb[8]);   // k = 32..63
  floatx4 acc[4];
#pragma unroll
  for (int i0 = 0; i0 < 4; i0++) {
    floatx4 z = {0.f, 0.f, 0.f, 0.f};
    z = __builtin_amdgcn_mfma_f32_16x16x32_bf16(aQ[i0][0], bq0, z, 0, 0, 0);
    z = __builtin_amdgcn_mfma_f32_16x16x32_bf16(aQ[i0][1], bq1, z, 0, 0, 0);
    acc[i0] = z;
  }

  // ---- RoPE (lane-local; partner feature i±32 = tile i0^2, same reg) ----
#pragma unroll
  for (int i0 = 0; i0 < 4; i0++) {
    const int p = i0 ^ 2;
    const float sg = (i0 < 2) ? -1.f : 1.f;   // i<32: -x2*sin ; i>=32: +x1*sin
    float r0 = acc[i0][0] * c[i0].x + sg * acc[p][0] * sn[i0].x;
    float r1 = acc[i0][1] * c[i0].y + sg * acc[p][1] * sn[i0].y;
    float r2 = acc[i0][2] * c[i0].z + sg * acc[p][2] * sn[i0].z;
    float r3 = acc[i0][3] * c[i0].w + sg * acc[p][3] * sn[i0].w;
    u32 lo = f2bf(r0) | (f2bf(r1) << 16);
    u32 hi = f2bf(r2) | (f2bf(r3) << 16);
    *(uint2*)&sh[t * 66 + i0 * 16 + quad * 4] = make_uint2(lo, hi);  // qr[t][i..i+3]
  }

  __builtin_amdgcn_wave_barrier();   // wave-synchronous LDS: DS pipe in-order per wave
  short8 br0 = *(const short8*)&sh[t * 66 + quad * 8];        // k 0..31
  short8 br1 = *(const short8*)&sh[t * 66 + 32 + quad * 8];   // k 32..63

  // ---- GEMM2 + store ----
#pragma unroll
  for (int o0 = 0; o0 < 4; o0++) {
    short8 aT0 = *(const short8*)(Qtb + (o0 * 16 + t) * 64 + quad * 8);
    short8 aT1 = *(const short8*)(Qtb + (o0 * 16 + t) * 64 + 32 + quad * 8);
    floatx4 z = {0.f, 0.f, 0.f, 0.f};
    z = __builtin_amdgcn_mfma_f32_16x16x32_bf16(aT0, br0, z, 0, 0, 0);
    z = __builtin_amdgcn_mfma_f32_16x16x32_bf16(aT1, br1, z, 0, 0, 0);
    *(float4*)(op + (token_base + t) * 64 + o0 * 16 + quad * 4) =
        make_float4(z[0], z[1], z[2], z[3]);
  }
}

extern "C" void kernel_launch(void* const* d_in, const int* in_sizes, int n_in,
                              void* d_out, int out_size, void* d_ws, size_t ws_size,
                              hipStream_t stream) {
  const float* q    = (const float*)d_in[0];
  const float* k    = (const float*)d_in[1];
  const float* cosp = (const float*)d_in[2];
  const float* sinp = (const float*)d_in[3];
  const float* vs   = (const float*)d_in[4];
  float* out = (float*)d_out;
  u16* Qb  = (u16*)d_ws;          // 64x64 bf16 Q
  u16* Qtb = Qb + 4096;           // 64x64 bf16 Q^T

  hipLaunchKernelGGL(hh_kernel, dim3(1), dim3(64), 0, stream, vs, Qb, Qtb);
  hipLaunchKernelGGL(rnrope_kernel, dim3(8192), dim3(256), 0, stream,
                     q, k, cosp, sinp, Qb, Qtb, out);
}